// Round 4
// baseline (123.397 us; speedup 1.0000x reference)
//
#include <hip/hip_runtime.h>

#define NB 128
#define NA 2
#define NH 128
#define NW 128
#define PLANE (NH * NW)            // 16384 floats per channel plane
#define RTHRESH 0.6f
#define OBJ_SCALE 5.0f
#define NBLK 2048                  // main-pass blocks, 8 cells/thread

__device__ __forceinline__ float sigm(float v) {
    return 1.0f / (1.0f + __expf(-v));
}

// Per-batch GT-box constants + best-anchor selection (tiny inputs, L1-hit,
// wave-uniform b -> compiler emits scalar loads).
__device__ __forceinline__ void batch_const(const float* __restrict__ target,
                                            const float* __restrict__ anchors,
                                            int b,
                                            float& gx, float& gy, float& gw, float& gh,
                                            int& bn, int& gxi, int& gyi) {
    float t0 = target[b * 4 + 0], t1 = target[b * 4 + 1];
    float t2 = target[b * 4 + 2], t3 = target[b * 4 + 3];
    gx = t0 * (float)NW;
    gy = t1 * (float)NH;
    gw = t2 * (float)NW;
    gh = t3 * (float)NH;
    float a0w = anchors[0], a0h = anchors[1];
    float a1w = anchors[2], a1h = anchors[3];
    float i0 = fminf(gw, a0w) * fminf(gh, a0h);
    float u0 = gw * gh + 1e-16f + a0w * a0h - i0;
    float i1 = fminf(gw, a1w) * fminf(gh, a1h);
    float u1 = gw * gh + 1e-16f + a1w * a1h - i1;
    bn  = (i1 / u1 > i0 / u0) ? 1 : 0;   // argmax picks FIRST max
    gxi = (int)gx;   // gt_x in (12.8, 115.2): trunc == floor, in-bounds
    gyi = (int)gy;
}

// Dense pass. 2048 blocks x 256 threads x 8 cells = 4,194,304 cells.
// Middle ground between r2 (16 cells, occupancy cliff) and r3 (4 cells,
// per-block overhead x4096): 10 upfront float4 loads = 10 KB in flight/wave
// at ~64-80 VGPR. Per-block partial writes (no same-address atomics — r1
// postmortem: those serialized at ~85us).
__global__ __launch_bounds__(256) void region_main(
        const float* __restrict__ out,
        const float* __restrict__ target,
        const float* __restrict__ anchors,
        float* __restrict__ psum,
        unsigned int* __restrict__ pcnt) {
    int tid = threadIdx.x;
    int bid = blockIdx.x;
    int slab = bid >> 3;           // (b, a) pair, 0..255
    int part = bid & 7;            // 2048-cell slice of the 16384-cell plane
    int b = slab >> 1, a = slab & 1;

    float gx, gy, gw, gh; int bn, gxi, gyi;
    batch_const(target, anchors, b, gx, gy, gw, gh, bn, gxi, gyi);
    float aw = anchors[a * 2 + 0];
    float ah = anchors[a * 2 + 1];

    const float* p0 = out + (size_t)(b * 10 + a * 5) * PLANE + part * 2048 + tid * 4;
    const float* p1 = p0 + 1024;

    // issue all 10 loads before any compute
    float4 vx0 = *(const float4*)(p0);
    float4 vy0 = *(const float4*)(p0 + 1 * PLANE);
    float4 vw0 = *(const float4*)(p0 + 2 * PLANE);
    float4 vh0 = *(const float4*)(p0 + 3 * PLANE);
    float4 vc0 = *(const float4*)(p0 + 4 * PLANE);
    float4 vx1 = *(const float4*)(p1);
    float4 vy1 = *(const float4*)(p1 + 1 * PLANE);
    float4 vw1 = *(const float4*)(p1 + 2 * PLANE);
    float4 vh1 = *(const float4*)(p1 + 3 * PLANE);
    float4 vc1 = *(const float4*)(p1 + 4 * PLANE);

    float gxm = gx - gw * 0.5f, gxM = gx + gw * 0.5f;
    float gym = gy - gh * 0.5f, gyM = gy + gh * 0.5f;
    float garea = gw * gh;
    bool a_sel = (a == bn);

    float lsum = 0.0f;
    int   lcnt = 0;

    const float* fx[2] = { (const float*)&vx0, (const float*)&vx1 };
    const float* fy[2] = { (const float*)&vy0, (const float*)&vy1 };
    const float* fw[2] = { (const float*)&vw0, (const float*)&vw1 };
    const float* fh[2] = { (const float*)&vh0, (const float*)&vh1 };
    const float* fc[2] = { (const float*)&vc0, (const float*)&vc1 };

#pragma unroll
    for (int g = 0; g < 2; ++g) {
        int pos0 = part * 2048 + g * 1024 + tid * 4;
        int i  = pos0 >> 7;                    // constant across e (tid*4%128<=124)
        int j0 = pos0 & 127;
        float fi = (float)i;
        bool row_sel = a_sel && (i == gyi);
#pragma unroll
        for (int e = 0; e < 4; ++e) {
            float px = sigm(fx[g][e]) + (float)(j0 + e);
            float py = sigm(fy[g][e]) + fi;
            float pw = __expf(fw[g][e]) * aw;
            float ph = __expf(fh[g][e]) * ah;
            float cf = sigm(fc[g][e]);

            float mx = fminf(px - pw * 0.5f, gxm);
            float Mx = fmaxf(px + pw * 0.5f, gxM);
            float my = fminf(py - ph * 0.5f, gym);
            float My = fmaxf(py + ph * 0.5f, gyM);
            float cw = pw + gw - (Mx - mx);
            float ch = ph + gh - (My - my);
            float iou = 0.0f;
            if (cw > 0.0f && ch > 0.0f) {
                float carea = cw * ch;
                iou = carea / (pw * ph + garea - carea);
            }
            bool noobj = (iou <= RTHRESH) && !(row_sel && (j0 + e) == gxi);
            if (noobj) { lsum += cf * cf; lcnt += 1; }
        }
    }

    // wave64 shuffle tree, then LDS across 4 waves, one store per block
#pragma unroll
    for (int off = 32; off > 0; off >>= 1) {
        lsum += __shfl_down(lsum, off);
        lcnt += __shfl_down(lcnt, off);
    }
    __shared__ float ssum[4];
    __shared__ int   scnt[4];
    int wid = tid >> 6, lane = tid & 63;
    if (lane == 0) { ssum[wid] = lsum; scnt[wid] = lcnt; }
    __syncthreads();
    if (tid == 0) {
        psum[bid] = ssum[0] + ssum[1] + ssum[2] + ssum[3];
        pcnt[bid] = (unsigned int)(scnt[0] + scnt[1] + scnt[2] + scnt[3]);
    }
}

// Final: reduce 2048 partials + 128 selected-cell losses. 1 block, 1024 thr.
__global__ __launch_bounds__(1024) void region_final(
        const float* __restrict__ out,
        const float* __restrict__ target,
        const float* __restrict__ anchors,
        const float* __restrict__ psum,
        const unsigned int* __restrict__ pcnt,
        float* __restrict__ loss_out) {
    int t = threadIdx.x;
    float s = 0.0f;
    unsigned int c = 0;
#pragma unroll
    for (int k = 0; k < NBLK / 1024; ++k) {
        s += psum[t + k * 1024];
        c += pcnt[t + k * 1024];
    }

    float v = 0.0f;
    if (t < NB) {
        int b = t;
        float gx, gy, gw, gh; int bn, gxi, gyi;
        batch_const(target, anchors, b, gx, gy, gw, gh, bn, gxi, gyi);
        float tx = gx - floorf(gx);
        float ty = gy - floorf(gy);
        float aw = anchors[bn * 2 + 0];
        float ah = anchors[bn * 2 + 1];
        float tw = __logf(gw / aw + 1e-16f);
        float th = __logf(gh / ah + 1e-16f);
        float scale = 2.0f - target[b * 4 + 2] * target[b * 4 + 3];

        size_t base = (size_t)(b * 10 + bn * 5) * PLANE + (size_t)gyi * NW + (size_t)gxi;
        float xs = sigm(out[base]);
        float ys = sigm(out[base + 1 * PLANE]);
        float wr = out[base + 2 * PLANE];
        float hr = out[base + 3 * PLANE];
        float cs = sigm(out[base + 4 * PLANE]);

        float dx = (xs - tx) * scale;
        float dy = (ys - ty) * scale;
        float dw = (wr - tw) * scale;
        float dh = (hr - th) * scale;
        float dc = cs - 1.0f;
        v = dx * dx + dy * dy + dw * dw + dh * dh + OBJ_SCALE * dc * dc;
    }

#pragma unroll
    for (int off = 32; off > 0; off >>= 1) {
        s += __shfl_down(s, off);
        c += __shfl_down(c, off);
        v += __shfl_down(v, off);
    }
    __shared__ float ss[16];
    __shared__ unsigned int sc[16];
    __shared__ float sv[16];
    int wid = t >> 6, lane = t & 63;
    if (lane == 0) { ss[wid] = s; sc[wid] = c; sv[wid] = v; }
    __syncthreads();
    if (t < 16) {
        s = ss[t]; c = sc[t]; v = sv[t];
#pragma unroll
        for (int off = 8; off > 0; off >>= 1) {
            s += __shfl_down(s, off);
            c += __shfl_down(c, off);
            v += __shfl_down(v, off);
        }
        if (t == 0)
            loss_out[0] = v * (1.0f / (float)NB) + s / (float)c;
    }
}

extern "C" void kernel_launch(void* const* d_in, const int* in_sizes, int n_in,
                              void* d_out, int out_size, void* d_ws, size_t ws_size,
                              hipStream_t stream) {
    const float* output  = (const float*)d_in[0];   // (128, 10, 128, 128) fp32
    const float* target  = (const float*)d_in[1];   // (128, 4)
    const float* anchors = (const float*)d_in[2];   // (2, 2)
    float* loss = (float*)d_out;

    // d_ws layout: [0,8K) float psum[2048]; [8K,16K) uint pcnt[2048].
    // Every slot written unconditionally -> no memset of poisoned ws needed.
    float* psum = (float*)d_ws;
    unsigned int* pcnt = (unsigned int*)((char*)d_ws + NBLK * sizeof(float));

    region_main<<<NBLK, 256, 0, stream>>>(output, target, anchors, psum, pcnt);
    region_final<<<1, 1024, 0, stream>>>(output, target, anchors, psum, pcnt, loss);
}

// Round 5
// 121.831 us; speedup vs baseline: 1.0129x; 1.0129x over previous
//
#include <hip/hip_runtime.h>

#define NB 128
#define NA 2
#define NH 128
#define NW 128
#define PLANE (NH * NW)            // 16384 floats per channel plane
#define OBJ_SCALE 5.0f
#define NBLK 1024                  // 4 blocks/CU, all co-resident (persistent)

// Fast sigmoid: v_exp + v_rcp (~1ulp). Reference tolerance is 0.68 absolute;
// rcp error contributes ~1e-7 relative to the loss. No v_div sequences.
__device__ __forceinline__ float sigm(float v) {
    return __builtin_amdgcn_rcpf(1.0f + __expf(-v));
}

// Per-batch GT-box constants + best-anchor selection (tiny inputs, L1-hit,
// wave-uniform b -> scalar loads). Full-precision divides kept here (affects
// argmax result, and it's wave-uniform / 128-thread work — cost is nil).
__device__ __forceinline__ void batch_const(const float* __restrict__ target,
                                            const float* __restrict__ anchors,
                                            int b,
                                            float& gx, float& gy, float& gw, float& gh,
                                            int& bn, int& gxi, int& gyi) {
    float t0 = target[b * 4 + 0], t1 = target[b * 4 + 1];
    float t2 = target[b * 4 + 2], t3 = target[b * 4 + 3];
    gx = t0 * (float)NW;
    gy = t1 * (float)NH;
    gw = t2 * (float)NW;
    gh = t3 * (float)NH;
    float a0w = anchors[0], a0h = anchors[1];
    float a1w = anchors[2], a1h = anchors[3];
    float i0 = fminf(gw, a0w) * fminf(gh, a0h);
    float u0 = gw * gh + 1e-16f + a0w * a0h - i0;
    float i1 = fminf(gw, a1w) * fminf(gh, a1h);
    float u1 = gw * gh + 1e-16f + a1w * a1h - i1;
    bn  = (i1 / u1 > i0 / u0) ? 1 : 0;   // argmax picks FIRST max
    gxi = (int)gx;   // gt_x in (12.8, 115.2): trunc == floor, in-bounds
    gyi = (int)gy;
}

// Dense pass. 1024 blocks x 256 threads x 16 cells = 4,194,304 cells.
// 4 blocks/CU co-resident for the whole kernel (no block turnover), each
// thread does 4 sweeps of 5 float4 loads with depth-1 register prefetch:
// sweep s+1's loads are issued before sweep s's compute consumes its data,
// so 5 loads/wave stay in flight continuously.
// Divide-free inner loop: iou<=0.6 tested as carea<=0.6*uarea (uarea>0
// always: uarea >= garea > 40); no-overlap => iou=0 => noobj true.
__global__ __launch_bounds__(256) void region_main(
        const float* __restrict__ out,
        const float* __restrict__ target,
        const float* __restrict__ anchors,
        float* __restrict__ psum,
        unsigned int* __restrict__ pcnt) {
    int tid = threadIdx.x;
    int bid = blockIdx.x;
    int slab = bid >> 2;           // (b, a) pair, 0..255
    int part = bid & 2 ? (bid & 3) : (bid & 3);  // quarter index 0..3
    part = bid & 3;
    int b = slab >> 1, a = slab & 1;

    float gx, gy, gw, gh; int bn, gxi, gyi;
    batch_const(target, anchors, b, gx, gy, gw, gh, bn, gxi, gyi);
    float aw = anchors[a * 2 + 0];
    float ah = anchors[a * 2 + 1];

    const float* pb = out + (size_t)(b * 10 + a * 5) * PLANE + part * 4096 + tid * 4;

    // prime the pipeline: sweep 0 loads
    float4 cx = *(const float4*)(pb);
    float4 cy = *(const float4*)(pb + 1 * PLANE);
    float4 cw4 = *(const float4*)(pb + 2 * PLANE);
    float4 ch4 = *(const float4*)(pb + 3 * PLANE);
    float4 cc = *(const float4*)(pb + 4 * PLANE);

    float gxm = gx - gw * 0.5f, gxM = gx + gw * 0.5f;
    float gym = gy - gh * 0.5f, gyM = gy + gh * 0.5f;
    float garea = gw * gh;
    float uthresh_k = 0.6f;
    bool a_sel = (a == bn);

    float lsum = 0.0f;
    int   lcnt = 0;

#pragma unroll
    for (int s = 0; s < 4; ++s) {
        float4 nx, ny, nw4, nh4, nc;
        if (s < 3) {   // prefetch next sweep before computing current
            const float* pn = pb + (s + 1) * 1024;
            nx  = *(const float4*)(pn);
            ny  = *(const float4*)(pn + 1 * PLANE);
            nw4 = *(const float4*)(pn + 2 * PLANE);
            nh4 = *(const float4*)(pn + 3 * PLANE);
            nc  = *(const float4*)(pn + 4 * PLANE);
        }

        int pos0 = part * 4096 + s * 1024 + tid * 4;
        int i  = pos0 >> 7;         // row, constant across e
        int j0 = pos0 & 127;
        float fi = (float)i;
        bool row_sel = a_sel && (i == gyi);

        const float* fx = (const float*)&cx;
        const float* fy = (const float*)&cy;
        const float* fw = (const float*)&cw4;
        const float* fh = (const float*)&ch4;
        const float* fc = (const float*)&cc;

#pragma unroll
        for (int e = 0; e < 4; ++e) {
            float px = sigm(fx[e]) + (float)(j0 + e);
            float py = sigm(fy[e]) + fi;
            float pw = __expf(fw[e]) * aw;
            float ph = __expf(fh[e]) * ah;
            float cf = sigm(fc[e]);

            float pwh = pw * 0.5f, phh = ph * 0.5f;
            float mx = fminf(px - pwh, gxm);
            float Mx = fmaxf(px + pwh, gxM);
            float my = fminf(py - phh, gym);
            float My = fmaxf(py + phh, gyM);
            float cw = pw + gw - (Mx - mx);
            float ch = ph + gh - (My - my);
            float carea = cw * ch;
            float uarea = pw * ph + garea - carea;
            bool noobj = (cw <= 0.0f) || (ch <= 0.0f) ||
                         (carea <= uthresh_k * uarea);
            noobj = noobj && !(row_sel && (j0 + e) == gxi);
            if (noobj) { lsum += cf * cf; lcnt += 1; }
        }

        if (s < 3) { cx = nx; cy = ny; cw4 = nw4; ch4 = nh4; cc = nc; }
    }

    // wave64 shuffle tree, then LDS across 4 waves, one store per block
#pragma unroll
    for (int off = 32; off > 0; off >>= 1) {
        lsum += __shfl_down(lsum, off);
        lcnt += __shfl_down(lcnt, off);
    }
    __shared__ float ssum[4];
    __shared__ int   scnt[4];
    int wid = tid >> 6, lane = tid & 63;
    if (lane == 0) { ssum[wid] = lsum; scnt[wid] = lcnt; }
    __syncthreads();
    if (tid == 0) {
        psum[bid] = ssum[0] + ssum[1] + ssum[2] + ssum[3];
        pcnt[bid] = (unsigned int)(scnt[0] + scnt[1] + scnt[2] + scnt[3]);
    }
}

// Final: reduce 1024 partials + 128 selected-cell losses. 1 block, 1024 thr.
__global__ __launch_bounds__(1024) void region_final(
        const float* __restrict__ out,
        const float* __restrict__ target,
        const float* __restrict__ anchors,
        const float* __restrict__ psum,
        const unsigned int* __restrict__ pcnt,
        float* __restrict__ loss_out) {
    int t = threadIdx.x;
    float s = psum[t];
    unsigned int c = pcnt[t];

    float v = 0.0f;
    if (t < NB) {
        int b = t;
        float gx, gy, gw, gh; int bn, gxi, gyi;
        batch_const(target, anchors, b, gx, gy, gw, gh, bn, gxi, gyi);
        float tx = gx - floorf(gx);
        float ty = gy - floorf(gy);
        float aw = anchors[bn * 2 + 0];
        float ah = anchors[bn * 2 + 1];
        float tw = __logf(gw / aw + 1e-16f);
        float th = __logf(gh / ah + 1e-16f);
        float scale = 2.0f - target[b * 4 + 2] * target[b * 4 + 3];

        size_t base = (size_t)(b * 10 + bn * 5) * PLANE + (size_t)gyi * NW + (size_t)gxi;
        float xs = sigm(out[base]);
        float ys = sigm(out[base + 1 * PLANE]);
        float wr = out[base + 2 * PLANE];
        float hr = out[base + 3 * PLANE];
        float cs = sigm(out[base + 4 * PLANE]);

        float dx = (xs - tx) * scale;
        float dy = (ys - ty) * scale;
        float dw = (wr - tw) * scale;
        float dh = (hr - th) * scale;
        float dc = cs - 1.0f;
        v = dx * dx + dy * dy + dw * dw + dh * dh + OBJ_SCALE * dc * dc;
    }

#pragma unroll
    for (int off = 32; off > 0; off >>= 1) {
        s += __shfl_down(s, off);
        c += __shfl_down(c, off);
        v += __shfl_down(v, off);
    }
    __shared__ float ss[16];
    __shared__ unsigned int sc[16];
    __shared__ float sv[16];
    int wid = t >> 6, lane = t & 63;
    if (lane == 0) { ss[wid] = s; sc[wid] = c; sv[wid] = v; }
    __syncthreads();
    if (t < 16) {
        s = ss[t]; c = sc[t]; v = sv[t];
#pragma unroll
        for (int off = 8; off > 0; off >>= 1) {
            s += __shfl_down(s, off);
            c += __shfl_down(c, off);
            v += __shfl_down(v, off);
        }
        if (t == 0)
            loss_out[0] = v * (1.0f / (float)NB) + s / (float)c;
    }
}

extern "C" void kernel_launch(void* const* d_in, const int* in_sizes, int n_in,
                              void* d_out, int out_size, void* d_ws, size_t ws_size,
                              hipStream_t stream) {
    const float* output  = (const float*)d_in[0];   // (128, 10, 128, 128) fp32
    const float* target  = (const float*)d_in[1];   // (128, 4)
    const float* anchors = (const float*)d_in[2];   // (2, 2)
    float* loss = (float*)d_out;

    // d_ws layout: [0,4K) float psum[1024]; [4K,8K) uint pcnt[1024].
    // Every slot written unconditionally -> no memset of poisoned ws needed.
    float* psum = (float*)d_ws;
    unsigned int* pcnt = (unsigned int*)((char*)d_ws + NBLK * sizeof(float));

    region_main<<<NBLK, 256, 0, stream>>>(output, target, anchors, psum, pcnt);
    region_final<<<1, 1024, 0, stream>>>(output, target, anchors, psum, pcnt, loss);
}